// Round 11
// baseline (122.021 us; speedup 1.0000x reference)
//
#include <hip/hip_runtime.h>
#include <stdint.h>
#include <math.h>

typedef float  f32x4 __attribute__((ext_vector_type(4)));
typedef float  f32x2 __attribute__((ext_vector_type(2)));
typedef short  s16x8 __attribute__((ext_vector_type(8)));
typedef short  s16x4 __attribute__((ext_vector_type(4)));

#define KC   1024
#define DD   256
#define NR   32768

// workspace layout (bytes)
#define WS_HIST   0         // 1024 x u32
#define WS_ACC    4096      // 2 x f32
#define WS_E2     8192      // 1024 x f32
#define WS_IDX    12288     // 32768 x i32
#define WS_PANEL  143360    // 1024*256 bf16 row-major (512 B/row)
#define WS_PART   671744    // 4 x 32768 x (f32 score, u32 idx)

// out layout (floats): [0]=loss, [1..8388608]=quantized, [8388609]=perplexity,
// [8388610..]=encodings
#define ENC_OFF   8388610ULL

// LDS layout inside k_argmin (bytes). A staging region (32 KB) is
// PROLOGUE-ONLY and overlaid by the 4 B buffers. 33 KB -> 4 blocks/CU.
#define A_OFF   0        // 64 rows x 512 B (bf16, swizzled), prologue only
#define B_OFF   0        // 4 x 8192 (16 codes x 512 B, swizzled) = 32768
#define E2_OFF  32768    // 256 x f32
#define SMEM_SZ 33792

#define GLD16(gp, lp) __builtin_amdgcn_global_load_lds(                      \
    (const __attribute__((address_space(1))) uint32_t*)(gp),                 \
    (__attribute__((address_space(3))) uint32_t*)(lp), 16, 0, 0)

#define WAITVM(N) asm volatile("s_waitcnt vmcnt(" #N ")" ::: "memory")
#define PHASEBAR() do { __builtin_amdgcn_s_barrier();                        \
                        asm volatile("" ::: "memory"); } while (0)

__device__ __forceinline__ short f2bf(float f) {
    uint32_t u = __builtin_bit_cast(uint32_t, f);
    uint32_t r = (u + 0x7FFFu + ((u >> 16) & 1u)) >> 16;   // RNE
    return (short)r;
}

// ---- kernel 0: bf16 codebook panel + e2[k] + zero hist/accums -------------
__global__ void k_prep(const float* __restrict__ emb, char* __restrict__ ws) {
    int tid = threadIdx.x;
    if (blockIdx.x == 0) {
        uint32_t* hist = (uint32_t*)(ws + WS_HIST);
        #pragma unroll
        for (int j = 0; j < 4; j++) hist[tid * 4 + j] = 0u;
        if (tid < 2) ((float*)(ws + WS_ACC))[tid] = 0.f;
    }
    int wid = tid >> 6, lane = tid & 63;
    int code = blockIdx.x * 4 + wid;
    const float* row = emb + (size_t)code * DD;
    f32x4 v = *(const f32x4*)(row + lane * 4);
    s16x4 b;
    b[0] = f2bf(v.x); b[1] = f2bf(v.y); b[2] = f2bf(v.z); b[3] = f2bf(v.w);
    *(s16x4*)((short*)(ws + WS_PANEL) + (size_t)code * DD + lane * 4) = b;
    float ss = v.x * v.x + v.y * v.y + v.z * v.z + v.w * v.w;
    #pragma unroll
    for (int off = 1; off < 64; off <<= 1) ss += __shfl_xor(ss, off);
    if (lane == 0) ((float*)(ws + WS_E2))[code] = ss;
}

// ---- kernel 1: distance GEMM + per-quarter argmin ---------------------------
// 1024 blocks x 256 thr (4 waves), 4 blocks/CU. Block = 128 rows x 256 codes
// (rowgrp = bid>>2, cq = bid&3). Wave w owns rows w*32..+31 (af[2][8]).
// B chunks (16 codes, 8 KB) in 4 LDS buffers via global_load_lds, depth-3
// counted vmcnt. Per-row partial (min,idx) written to WS_PART[cq].
__global__ __launch_bounds__(256, 4) void k_argmin(const float* __restrict__ latents,
                                                   char* __restrict__ ws) {
    const char*  panelb = (const char*)(ws + WS_PANEL);
    const float* e2g    = (const float*)(ws + WS_E2);
    float*       acc    = (float*)(ws + WS_ACC);

    __shared__ __align__(16) char smem[SMEM_SZ];

    int t      = threadIdx.x;
    int lane   = t & 63;
    int wid    = t >> 6;
    int g      = lane >> 4, r16 = lane & 15;
    int rowgrp = blockIdx.x >> 2;
    int cq     = blockIdx.x & 3;
    int nbase  = rowgrp * 128;
    int b      = nbase >> 10;
    int hwbase = nbase & 1023;
    const char* pbase = panelb + (size_t)cq * 131072;   // this quarter's 256 codes

    // ---- e2 (this quarter) -> LDS -----------------------------------------
    ((float*)(smem + E2_OFF))[t] = e2g[cq * 256 + t];

    // ---- stage A in two 64-row pieces; owning wave-pair extracts -----------
    float xs = 0.f;
    s16x8 af[2][8];
    int rg = (t & 15) * 4;            // 4 rows per thread within piece
    int dp = (t >> 4) * 2;            // even d base

    #pragma unroll 1
    for (int h = 0; h < 2; h++) {
        const float* base = latents + (size_t)b * 262144 + hwbase + h * 64 + rg;
        #pragma unroll
        for (int i = 0; i < 8; i++) {
            int d = dp + i * 32;
            f32x4 v0 = *(const f32x4*)(base + (size_t)d * 1024);
            f32x4 v1 = *(const f32x4*)(base + (size_t)(d + 1) * 1024);
            xs += v0.x*v0.x + v0.y*v0.y + v0.z*v0.z + v0.w*v0.w;
            xs += v1.x*v1.x + v1.y*v1.y + v1.z*v1.z + v1.w*v1.w;
            int qb = d >> 3;
            #pragma unroll
            for (int q = 0; q < 4; q++) {
                int slot = rg + q;
                uint32_t pk = (uint32_t)(uint16_t)f2bf(v0[q])
                            | ((uint32_t)(uint16_t)f2bf(v1[q]) << 16);
                int quad = qb ^ (slot & 7) ^ ((slot >> 3) & 7);
                *(uint32_t*)(smem + A_OFF + slot * 512 + quad * 16 + (d & 6) * 2) = pk;
            }
        }
        __syncthreads();
        if ((wid >> 1) == h) {          // waves 2h,2h+1 own this piece
            int slotbase = (wid & 1) * 32;
            #pragma unroll
            for (int rt = 0; rt < 2; rt++) {
                #pragma unroll
                for (int kt = 0; kt < 8; kt++) {
                    int slot = slotbase + rt * 16 + r16;
                    int quad = (kt * 4 + g) ^ (slot & 7) ^ ((slot >> 3) & 7);
                    af[rt][kt] = *(const s16x8*)(smem + A_OFF + slot * 512 + quad * 16);
                }
            }
        }
        __syncthreads();                // after h=1: all waves done with A region
    }
    if (cq == 0) {
        #pragma unroll
        for (int off = 1; off < 64; off <<= 1) xs += __shfl_xor(xs, off);
        if (lane == 0) atomicAdd(acc + 0, xs);
    }

    // ---- hoisted loop-invariant addressing ---------------------------------
    uint32_t doff0 = wid * 1024;
    uint32_t doff1 = 4096 + wid * 1024;
    uint32_t so0 = doff0 + lane * 16;
    uint32_t so1 = doff1 + lane * 16;
    uint32_t ssw0 = so0 ^ (((so0 >> 9) & 7u) << 4);
    uint32_t ssw1 = so1 ^ (((so1 >> 9) & 7u) << 4);
    uint32_t bfoff[8];
    #pragma unroll
    for (int kt = 0; kt < 8; kt++)
        bfoff[kt] = (uint32_t)(r16 * 512)
                  + (((uint32_t)(kt * 64 + g * 16)) ^ (((uint32_t)(r16 & 7)) << 4));

    // ---- chunk loop: 16 chunks of 16 codes, depth-3 counted vmcnt ----------
    float vmin[2][4];
    int   vidx[2][4];
    #pragma unroll
    for (int rt = 0; rt < 2; rt++)
        #pragma unroll
        for (int j = 0; j < 4; j++) { vmin[rt][j] = 3.4e38f; vidx[rt][j] = 0; }

    const float* E2l = (const float*)(smem + E2_OFF);
    int codeglob = cq * 256;

    auto stage = [&](int c) {
        const char* srcc = pbase + (size_t)c * 8192;
        char* dstb = smem + B_OFF + (size_t)(c & 3) * 8192;
        GLD16(srcc + ssw0, dstb + doff0);
        GLD16(srcc + ssw1, dstb + doff1);
    };
    auto compute = [&](int c) {
        int cbase = c * 16;
        float e2c = E2l[cbase + r16];
        const char* Bc = smem + B_OFF + (size_t)(c & 3) * 8192;
        s16x8 bf[8];
        #pragma unroll
        for (int kt = 0; kt < 8; kt++) bf[kt] = *(const s16x8*)(Bc + bfoff[kt]);
        #pragma unroll
        for (int rt = 0; rt < 2; rt++) {
            f32x4 a4 = {0.f, 0.f, 0.f, 0.f};
            #pragma unroll
            for (int kt = 0; kt < 8; kt++)
                a4 = __builtin_amdgcn_mfma_f32_16x16x32_bf16(af[rt][kt], bf[kt], a4, 0, 0, 0);
            #pragma unroll
            for (int j = 0; j < 4; j++) {
                float s = e2c - 2.f * a4[j];
                bool better = s < vmin[rt][j];
                vmin[rt][j] = better ? s : vmin[rt][j];
                vidx[rt][j] = better ? (codeglob + cbase + r16) : vidx[rt][j];
            }
        }
    };

    // prologue: fill pipeline (3 chunks in flight = 6 loads/thread)
    stage(0); stage(1); stage(2);
    #pragma unroll 1
    for (int c = 0; c < 13; ++c) {
        WAITVM(4);            // own chunk-c loads landed (2 chunks in flight)
        PHASEBAR();           // all waves' chunk-c loads landed
        compute(c);
        stage(c + 3);         // overwrites buf (c-1)&3: readers done pre-barrier
    }
    WAITVM(4); PHASEBAR(); compute(13);
    WAITVM(2); PHASEBAR(); compute(14);
    WAITVM(0); PHASEBAR(); compute(15);

    // ---- per-wave argmin, write partial (score,idx) pairs ------------------
    uint2* part = (uint2*)(ws + WS_PART) + (size_t)cq * NR;
    #pragma unroll
    for (int rt = 0; rt < 2; rt++) {
        #pragma unroll
        for (int j = 0; j < 4; j++) {
            float s = vmin[rt][j]; int ii = vidx[rt][j];
            #pragma unroll
            for (int off = 1; off < 16; off <<= 1) {
                float os = __shfl_xor(s, off);
                int   oi = __shfl_xor(ii, off);
                if (os < s || (os == s && oi < ii)) { s = os; ii = oi; }
            }
            if (r16 == 0) {
                int n = nbase + wid * 32 + rt * 16 + g * 4 + j;
                uint2 pv;
                pv.x = __builtin_bit_cast(uint32_t, s);
                pv.y = (uint32_t)ii;
                part[n] = pv;
            }
        }
    }
}

// ---- kernel 1b: combine 4 code-quarter partials; hist + minsum -------------
__global__ void k_comb(char* __restrict__ ws) {
    const uint2* part = (const uint2*)(ws + WS_PART);
    uint32_t* hist = (uint32_t*)(ws + WS_HIST);
    float*    acc  = (float*)(ws + WS_ACC);
    int*      idxo = (int*)(ws + WS_IDX);
    int n = blockIdx.x * 256 + threadIdx.x;
    uint2 p0 = part[n];
    uint2 p1 = part[NR + n];
    uint2 p2 = part[2 * NR + n];
    uint2 p3 = part[3 * NR + n];
    float s  = __builtin_bit_cast(float, p0.x);
    int  ii  = (int)p0.y;
    float s1 = __builtin_bit_cast(float, p1.x);
    if (s1 < s) { s = s1; ii = (int)p1.y; }
    float s2 = __builtin_bit_cast(float, p2.x);
    if (s2 < s) { s = s2; ii = (int)p2.y; }
    float s3 = __builtin_bit_cast(float, p3.x);
    if (s3 < s) { s = s3; ii = (int)p3.y; }
    idxo[n] = ii;
    atomicAdd(hist + ii, 1u);
    #pragma unroll
    for (int off = 1; off < 64; off <<= 1) s += __shfl_xor(s, off);
    if ((threadIdx.x & 63) == 0) atomicAdd(acc + 1, s);
}

// ---- kernel 2: quantized output (gather + transpose to [B,D,H,W]) ---------
__global__ void k_quant(const float* __restrict__ emb, const char* __restrict__ ws,
                        float* __restrict__ out) {
    const int* idx = (const int*)(ws + WS_IDX);
    int tid = threadIdx.x;
    int dg  = blockIdx.x & 63;
    int hwt = (blockIdx.x >> 6) & 3;
    int b   = blockIdx.x >> 8;
    int hw  = hwt * 256 + tid;
    int n   = b * 1024 + hw;
    int code = idx[n];
    f32x4 v = *(const f32x4*)(emb + (size_t)code * 256 + dg * 4);
    float* dst = out + 1 + (size_t)b * 262144 + (size_t)dg * 4096 + hw;
    dst[0] = v.x; dst[1024] = v.y; dst[2048] = v.z; dst[3072] = v.w;
}

// ---- kernel 3: one-hot encodings (zeros + ones fused, 128 MB stream) ------
__global__ void k_onehot(const char* __restrict__ ws, float* __restrict__ out) {
    const int* idx = (const int*)(ws + WS_IDX);
    __shared__ int lidx[8];
    int tid = threadIdx.x;
    int rbase = blockIdx.x * 8;
    if (tid < 8) lidx[tid] = idx[rbase + tid];
    __syncthreads();
    f32x2* enc = (f32x2*)(out + ENC_OFF);
    #pragma unroll
    for (int j = 0; j < 16; j++) {
        int linear = j * 256 + tid;
        int rl = linear >> 9, c2 = linear & 511;
        int id = lidx[rl];
        f32x2 v;
        v.x = (2 * c2     == id) ? 1.f : 0.f;
        v.y = (2 * c2 + 1 == id) ? 1.f : 0.f;
        enc[(size_t)(rbase + rl) * 512 + c2] = v;
    }
}

// ---- kernel 4: loss + perplexity ------------------------------------------
__global__ void k_final(const char* __restrict__ ws, float* __restrict__ out) {
    __shared__ float red[256];
    const uint32_t* hist = (const uint32_t*)(ws + WS_HIST);
    const float*    acc  = (const float*)(ws + WS_ACC);
    int tid = threadIdx.x;
    float part = 0.f;
    #pragma unroll
    for (int j = 0; j < 4; j++) {
        float p = (float)hist[tid * 4 + j] * (1.f / 32768.f);
        part += p * logf(p + 1e-10f);
    }
    red[tid] = part;
    __syncthreads();
    for (int s = 128; s > 0; s >>= 1) {
        if (tid < s) red[tid] += red[tid + s];
        __syncthreads();
    }
    if (tid == 0) {
        out[8388609] = expf(-red[0]);                              // perplexity
        out[0] = 1.25f * (acc[0] + acc[1]) * (1.f / 8388608.f);    // loss
    }
}

extern "C" void kernel_launch(void* const* d_in, const int* in_sizes, int n_in,
                              void* d_out, int out_size, void* d_ws, size_t ws_size,
                              hipStream_t stream) {
    const float* latents = (const float*)d_in[0];
    const float* emb     = (const float*)d_in[1];
    float* out = (float*)d_out;
    char*  ws  = (char*)d_ws;

    hipLaunchKernelGGL(k_prep,   dim3(256),  dim3(256), 0, stream, emb, ws);
    hipLaunchKernelGGL(k_argmin, dim3(1024), dim3(256), 0, stream, latents, ws);
    hipLaunchKernelGGL(k_comb,   dim3(128),  dim3(256), 0, stream, ws);
    hipLaunchKernelGGL(k_quant,  dim3(8192), dim3(256), 0, stream, emb, ws, out);
    hipLaunchKernelGGL(k_onehot, dim3(4096), dim3(256), 0, stream, ws, out);
    hipLaunchKernelGGL(k_final,  dim3(1),    dim3(256), 0, stream, ws, out);
}

// Round 12
// 89.184 us; speedup vs baseline: 1.3682x; 1.3682x over previous
//
#include <hip/hip_runtime.h>
#include <stdint.h>
#include <math.h>

typedef float  f32x4 __attribute__((ext_vector_type(4)));
typedef float  f32x2 __attribute__((ext_vector_type(2)));
typedef short  s16x8 __attribute__((ext_vector_type(8)));
typedef short  s16x4 __attribute__((ext_vector_type(4)));

#define KC   1024
#define DD   256
#define NR   32768

// workspace layout (bytes)
#define WS_HIST   0         // 1024 x u32
#define WS_ACC    4096      // 2 x f32
#define WS_E2     8192      // 1024 x f32
#define WS_IDX    12288     // 32768 x i32
#define WS_PANEL  143360    // 1024*256 bf16 row-major (512 B/row)
#define WS_PART   671744    // 2 x 32768 x (f32 score, u32 idx)

// out layout (floats): [0]=loss, [1..8388608]=quantized, [8388609]=perplexity,
// [8388610..]=encodings
#define ENC_OFF   8388610ULL

// LDS layout inside k_argmin (bytes)
#define A_OFF   0        // 64 rows x 512 B (bf16, swizzled)
#define B_OFF   32768    // 4 x 8192 (16 codes x 512 B, swizzled)
#define E2_OFF  65536    // 512 x f32
#define SMEM_SZ 67584

#define GLD16(gp, lp) __builtin_amdgcn_global_load_lds(                      \
    (const __attribute__((address_space(1))) uint32_t*)(gp),                 \
    (__attribute__((address_space(3))) uint32_t*)(lp), 16, 0, 0)

#define WAITVM(N) asm volatile("s_waitcnt vmcnt(" #N ")" ::: "memory")
#define PHASEBAR() do { __builtin_amdgcn_s_barrier();                        \
                        __builtin_amdgcn_sched_barrier(0); } while (0)

__device__ __forceinline__ short f2bf(float f) {
    uint32_t u = __builtin_bit_cast(uint32_t, f);
    uint32_t r = (u + 0x7FFFu + ((u >> 16) & 1u)) >> 16;   // RNE
    return (short)r;
}

// ---- kernel 0: bf16 codebook panel + e2[k] + zero hist/accums -------------
// Panel/e2 written NON-TEMPORAL so readers don't chase dirty cross-XCD L2.
__global__ void k_prep(const float* __restrict__ emb, char* __restrict__ ws) {
    int tid = threadIdx.x;
    if (blockIdx.x == 0) {
        uint32_t* hist = (uint32_t*)(ws + WS_HIST);
        #pragma unroll
        for (int j = 0; j < 4; j++) hist[tid * 4 + j] = 0u;
        if (tid < 2) ((float*)(ws + WS_ACC))[tid] = 0.f;
    }
    int wid = tid >> 6, lane = tid & 63;
    int code = blockIdx.x * 4 + wid;
    const float* row = emb + (size_t)code * DD;
    f32x4 v = *(const f32x4*)(row + lane * 4);
    uint32_t lo = (uint32_t)(uint16_t)f2bf(v.x) | ((uint32_t)(uint16_t)f2bf(v.y) << 16);
    uint32_t hi = (uint32_t)(uint16_t)f2bf(v.z) | ((uint32_t)(uint16_t)f2bf(v.w) << 16);
    uint32_t* dst = (uint32_t*)((short*)(ws + WS_PANEL) + (size_t)code * DD + lane * 4);
    __builtin_nontemporal_store(lo, dst);
    __builtin_nontemporal_store(hi, dst + 1);
    float ss = v.x * v.x + v.y * v.y + v.z * v.z + v.w * v.w;
    #pragma unroll
    for (int off = 1; off < 64; off <<= 1) ss += __shfl_xor(ss, off);
    if (lane == 0)
        __builtin_nontemporal_store(ss, (float*)(ws + WS_E2) + code);
}

// ---- kernel 1: distance GEMM + per-half argmin -----------------------------
// 512 blocks x 256 thr (4 waves), 2 blocks/CU (all 512 co-resident).
// Block = 128 rows x 512 codes: rowgrp = bid & 255, chalf = bid >> 8
// (so the two blocks sharing A-rows sit on the SAME XCD).
// Chunk order PHASE-STAGGERED per rowgrp: spreads the B-panel demand so
// no cross-grid convoy on the same lines; L2 warms once, then all hits.
__global__ __launch_bounds__(256, 2) void k_argmin(const float* __restrict__ latents,
                                                   char* __restrict__ ws) {
    const char*  panelb = (const char*)(ws + WS_PANEL);
    const float* e2g    = (const float*)(ws + WS_E2);
    float*       acc    = (float*)(ws + WS_ACC);

    __shared__ __align__(16) char smem[SMEM_SZ];

    int t      = threadIdx.x;
    int lane   = t & 63;
    int wid    = t >> 6;
    int g      = lane >> 4, r16 = lane & 15;
    int rowgrp = blockIdx.x & 255;
    int chalf  = blockIdx.x >> 8;
    int nbase  = rowgrp * 128;
    int b      = nbase >> 10;
    int hwbase = nbase & 1023;
    int phase  = rowgrp & 31;
    const char* pbase = panelb + (size_t)chalf * 262144;   // this half's codes

    // ---- e2 (this half) -> LDS --------------------------------------------
    if (t < 128) {
        f32x4 ev = *(const f32x4*)(e2g + chalf * 512 + t * 4);
        *(f32x4*)(smem + E2_OFF + t * 16) = ev;
    }

    // ---- stage A in two 64-row pieces; owning wave-pair extracts -----------
    float xs = 0.f;
    s16x8 af[2][8];
    int rg = (t & 15) * 4;
    int dp = (t >> 4) * 2;

    #pragma unroll
    for (int h = 0; h < 2; h++) {
        const float* base = latents + (size_t)b * 262144 + hwbase + h * 64 + rg;
        #pragma unroll
        for (int i = 0; i < 8; i++) {
            int d = dp + i * 32;
            f32x4 v0 = *(const f32x4*)(base + (size_t)d * 1024);
            f32x4 v1 = *(const f32x4*)(base + (size_t)(d + 1) * 1024);
            xs += v0.x*v0.x + v0.y*v0.y + v0.z*v0.z + v0.w*v0.w;
            xs += v1.x*v1.x + v1.y*v1.y + v1.z*v1.z + v1.w*v1.w;
            int qb = d >> 3;
            #pragma unroll
            for (int q = 0; q < 4; q++) {
                int slot = rg + q;
                uint32_t pk = (uint32_t)(uint16_t)f2bf(v0[q])
                            | ((uint32_t)(uint16_t)f2bf(v1[q]) << 16);
                int quad = qb ^ (slot & 7) ^ ((slot >> 3) & 7);
                *(uint32_t*)(smem + A_OFF + slot * 512 + quad * 16 + (d & 6) * 2) = pk;
            }
        }
        __syncthreads();
        if ((wid >> 1) == h) {
            int slotbase = (wid & 1) * 32;
            #pragma unroll
            for (int rt = 0; rt < 2; rt++) {
                #pragma unroll
                for (int kt = 0; kt < 8; kt++) {
                    int slot = slotbase + rt * 16 + r16;
                    int quad = (kt * 4 + g) ^ (slot & 7) ^ ((slot >> 3) & 7);
                    af[rt][kt] = *(const s16x8*)(smem + A_OFF + slot * 512 + quad * 16);
                }
            }
        }
        __syncthreads();
    }
    if (chalf == 0) {
        #pragma unroll
        for (int off = 1; off < 64; off <<= 1) xs += __shfl_xor(xs, off);
        if (lane == 0) atomicAdd(acc + 0, xs);
    }

    // ---- pipelined chunk loop: depth-3 counted vmcnt, phase-staggered ------
    float vmin[2][4];
    int   vidx[2][4];
    #pragma unroll
    for (int rt = 0; rt < 2; rt++)
        #pragma unroll
        for (int j = 0; j < 4; j++) { vmin[rt][j] = 3.4e38f; vidx[rt][j] = 0; }

    const float* E2l = (const float*)(smem + E2_OFF);
    int codeglob = chalf * 512;

    auto stage = [&](int c) {
        const char* srcc = pbase + (size_t)c * 8192;
        char* dstb = smem + B_OFF + (size_t)(c & 3) * 8192;
        #pragma unroll
        for (int i = 0; i < 2; i++) {
            uint32_t off = i * 4096 + wid * 1024;
            uint32_t so  = off + lane * 16;
            uint32_t ssw = so ^ (((so >> 9) & 7u) << 4);
            GLD16(srcc + ssw, dstb + off);
        }
    };
    auto compute = [&](int c) {
        int cbase = c * 16;
        float e2c = E2l[cbase + r16];
        const char* Bc = smem + B_OFF + (size_t)(c & 3) * 8192;
        s16x8 bf[8];
        #pragma unroll
        for (int kt = 0; kt < 8; kt++) {
            uint32_t byte = (uint32_t)(r16 * 512)
                          + (((uint32_t)(kt * 64 + g * 16)) ^ (((uint32_t)(r16 & 7)) << 4));
            bf[kt] = *(const s16x8*)(Bc + byte);
        }
        #pragma unroll
        for (int rt = 0; rt < 2; rt++) {
            f32x4 a4 = {0.f, 0.f, 0.f, 0.f};
            #pragma unroll
            for (int kt = 0; kt < 8; kt++)
                a4 = __builtin_amdgcn_mfma_f32_16x16x32_bf16(af[rt][kt], bf[kt], a4, 0, 0, 0);
            #pragma unroll
            for (int j = 0; j < 4; j++) {
                float s = e2c - 2.f * a4[j];
                bool better = s < vmin[rt][j];
                vmin[rt][j] = better ? s : vmin[rt][j];
                vidx[rt][j] = better ? (codeglob + cbase + r16) : vidx[rt][j];
            }
        }
    };

    // prologue: fill pipeline (3 chunks in flight)
    stage(phase); stage((phase + 1) & 31); stage((phase + 2) & 31);
    #pragma unroll 1
    for (int c = 0; c < 29; ++c) {
        WAITVM(4);            // own chunk-c loads landed (2 chunks in flight)
        PHASEBAR();           // all waves' chunk-c loads landed
        compute((c + phase) & 31);
        stage((c + 3 + phase) & 31);   // overwrites buf readers finished with
    }
    WAITVM(4); PHASEBAR(); compute((29 + phase) & 31);
    WAITVM(2); PHASEBAR(); compute((30 + phase) & 31);
    WAITVM(0); PHASEBAR(); compute((31 + phase) & 31);

    // ---- per-wave argmin, write partial (score,idx) pairs ------------------
    uint2* part = (uint2*)(ws + WS_PART) + (size_t)chalf * NR;
    #pragma unroll
    for (int rt = 0; rt < 2; rt++) {
        #pragma unroll
        for (int j = 0; j < 4; j++) {
            float s = vmin[rt][j]; int ii = vidx[rt][j];
            #pragma unroll
            for (int off = 1; off < 16; off <<= 1) {
                float os = __shfl_xor(s, off);
                int   oi = __shfl_xor(ii, off);
                if (os < s || (os == s && oi < ii)) { s = os; ii = oi; }
            }
            if (r16 == 0) {
                int n = nbase + wid * 32 + rt * 16 + g * 4 + j;
                uint2 pv;
                pv.x = __builtin_bit_cast(uint32_t, s);
                pv.y = (uint32_t)ii;
                part[n] = pv;
            }
        }
    }
}

// ---- kernel 1b: combine code-half partials; hist + minsum ------------------
__global__ void k_comb(char* __restrict__ ws) {
    const uint2* part = (const uint2*)(ws + WS_PART);
    uint32_t* hist = (uint32_t*)(ws + WS_HIST);
    float*    acc  = (float*)(ws + WS_ACC);
    int*      idxo = (int*)(ws + WS_IDX);
    int n = blockIdx.x * 256 + threadIdx.x;
    uint2 p0 = part[n];
    uint2 p1 = part[NR + n];
    float s0 = __builtin_bit_cast(float, p0.x);
    float s1 = __builtin_bit_cast(float, p1.x);
    float s = (s1 < s0) ? s1 : s0;
    int  ii = (s1 < s0) ? (int)p1.y : (int)p0.y;
    idxo[n] = ii;
    atomicAdd(hist + ii, 1u);
    #pragma unroll
    for (int off = 1; off < 64; off <<= 1) s += __shfl_xor(s, off);
    if ((threadIdx.x & 63) == 0) atomicAdd(acc + 1, s);
}

// ---- kernel 2: quantized output (gather + transpose to [B,D,H,W]) ---------
__global__ void k_quant(const float* __restrict__ emb, const char* __restrict__ ws,
                        float* __restrict__ out) {
    const int* idx = (const int*)(ws + WS_IDX);
    int tid = threadIdx.x;
    int dg  = blockIdx.x & 63;
    int hwt = (blockIdx.x >> 6) & 3;
    int b   = blockIdx.x >> 8;
    int hw  = hwt * 256 + tid;
    int n   = b * 1024 + hw;
    int code = idx[n];
    f32x4 v = *(const f32x4*)(emb + (size_t)code * 256 + dg * 4);
    float* dst = out + 1 + (size_t)b * 262144 + (size_t)dg * 4096 + hw;
    dst[0] = v.x; dst[1024] = v.y; dst[2048] = v.z; dst[3072] = v.w;
}

// ---- kernel 3: one-hot encodings (zeros + ones fused, 128 MB stream) ------
__global__ void k_onehot(const char* __restrict__ ws, float* __restrict__ out) {
    const int* idx = (const int*)(ws + WS_IDX);
    __shared__ int lidx[8];
    int tid = threadIdx.x;
    int rbase = blockIdx.x * 8;
    if (tid < 8) lidx[tid] = idx[rbase + tid];
    __syncthreads();
    f32x2* enc = (f32x2*)(out + ENC_OFF);
    #pragma unroll
    for (int j = 0; j < 16; j++) {
        int linear = j * 256 + tid;
        int rl = linear >> 9, c2 = linear & 511;
        int id = lidx[rl];
        f32x2 v;
        v.x = (2 * c2     == id) ? 1.f : 0.f;
        v.y = (2 * c2 + 1 == id) ? 1.f : 0.f;
        enc[(size_t)(rbase + rl) * 512 + c2] = v;
    }
}

// ---- kernel 4: loss + perplexity ------------------------------------------
__global__ void k_final(const char* __restrict__ ws, float* __restrict__ out) {
    __shared__ float red[256];
    const uint32_t* hist = (const uint32_t*)(ws + WS_HIST);
    const float*    acc  = (const float*)(ws + WS_ACC);
    int tid = threadIdx.x;
    float part = 0.f;
    #pragma unroll
    for (int j = 0; j < 4; j++) {
        float p = (float)hist[tid * 4 + j] * (1.f / 32768.f);
        part += p * logf(p + 1e-10f);
    }
    red[tid] = part;
    __syncthreads();
    for (int s = 128; s > 0; s >>= 1) {
        if (tid < s) red[tid] += red[tid + s];
        __syncthreads();
    }
    if (tid == 0) {
        out[8388609] = expf(-red[0]);                              // perplexity
        out[0] = 1.25f * (acc[0] + acc[1]) * (1.f / 8388608.f);    // loss
    }
}

extern "C" void kernel_launch(void* const* d_in, const int* in_sizes, int n_in,
                              void* d_out, int out_size, void* d_ws, size_t ws_size,
                              hipStream_t stream) {
    const float* latents = (const float*)d_in[0];
    const float* emb     = (const float*)d_in[1];
    float* out = (float*)d_out;
    char*  ws  = (char*)d_ws;

    hipLaunchKernelGGL(k_prep,   dim3(256),  dim3(256), 0, stream, emb, ws);
    hipLaunchKernelGGL(k_argmin, dim3(512),  dim3(256), 0, stream, latents, ws);
    hipLaunchKernelGGL(k_comb,   dim3(128),  dim3(256), 0, stream, ws);
    hipLaunchKernelGGL(k_quant,  dim3(8192), dim3(256), 0, stream, emb, ws, out);
    hipLaunchKernelGGL(k_onehot, dim3(4096), dim3(256), 0, stream, ws, out);
    hipLaunchKernelGGL(k_final,  dim3(1),    dim3(256), 0, stream, ws, out);
}